// Round 11
// baseline (221.143 us; speedup 1.0000x reference)
//
#include <hip/hip_runtime.h>

#define OUT_SZ 299
#define PLANE (OUT_SZ * OUT_SZ)   // 89401
#define RPB 23                    // output rows per block: 23 * 13 = 299
#define CHUNKS 13
#define TSTRIDE 201               // tmp row stride in dwords (odd; >= wcI+1, wcI<=199)

__global__ __launch_bounds__(320) void crop_resize_kernel(
    const float* __restrict__ x,   // (32, 3, 299, 299)
    const int*   __restrict__ f,   // (32, 16, 4) = tlx, tly, brx, bry
    float*       __restrict__ out) // (32, 16, 3, 299, 299)
{
    __shared__ float tmp[RPB * TSTRIDE];   // 18492 B: row-interped crop rows

    const int t     = threadIdx.x;
    const int chunk = blockIdx.x;    // 0..12
    const int sg    = blockIdx.y;    // s*16 + g
    const int s     = sg >> 4;

    // Box is block-uniform -> scalar loads.
    const int4 box = *reinterpret_cast<const int4*>(f + (size_t)sg * 4);
    const int tlx = box.x, tly = box.y, brx = box.z, bry = box.w;
    const int hcI = brx - tlx, wcI = bry - tly;
    const float hc = (float)hcI, wc = (float)wcI;

    const int i0 = chunk * RPB;

    // Lane table: lanes 0..22 of EVERY wave hold row info for output row i0+rr.
    // Uniform control flow (all threads execute).
    const int lane = t & 63;
    int v_r0e, v_r1e;
    float v_wr;
    {
        float sr  = fminf(fmaxf(((float)(i0 + lane) + 0.5f) * hc / (float)OUT_SZ
                                - 0.5f, 0.0f), hc - 1.0f);
        float r0f = floorf(sr);
        v_wr = sr - r0f;
        int r0l = (int)r0f;
        int r1l = min(r0l + 1, hcI - 1);
        v_r0e = (r0l + tlx) * OUT_SZ + tly;   // plane-local offset of crop row r0
        v_r1e = (r1l + tlx) * OUT_SZ + tly;
    }

    // Hoist ALL readlanes into uniform control flow (convergent-op safety).
    // Wave-uniform scalars, statically indexed -> SGPR arrays.
    int   sr0e[RPB], sr1e[RPB];
    float srw[RPB];
    #pragma unroll
    for (int rr = 0; rr < RPB; ++rr) {
        sr0e[rr] = __builtin_amdgcn_readlane(v_r0e, rr);
        sr1e[rr] = __builtin_amdgcn_readlane(v_r1e, rr);
        srw[rr]  = __int_as_float(
                       __builtin_amdgcn_readlane(__float_as_int(v_wr), rr));
    }

    // Per-output-column precompute (registers only, channel-independent).
    float sc  = fminf(fmaxf(((float)t + 0.5f) * wc / (float)OUT_SZ - 0.5f,
                            0.0f), wc - 1.0f);
    float c0f = floorf(sc);
    const int   c0  = (int)c0f;          // crop-local, in [0, wcI-1]
    const float wcl = sc - c0f;
    const int   jl  = min(t, wcI - 1);   // phase-1 load col (t==wcI -> pad dup)

    const float* __restrict__ imgS = x   + (size_t)s  * 3 * PLANE;
    float*       __restrict__ outS = out + (size_t)sg * 3 * PLANE
                                   + (size_t)i0 * OUT_SZ + t;

    // Channel loop: geometry reused; tmp recycled with barriers.
    for (int ch = 0; ch < 3; ++ch) {
        const float* __restrict__ img = imgS + (size_t)ch * PLANE;

        // Phase 1: vertical (row) interp over crop columns — COALESCED loads.
        if (t <= wcI) {                  // plain loads/stores only inside
            #pragma unroll
            for (int rr = 0; rr < RPB; ++rr) {
                float a = img[sr0e[rr] + jl];    // scalar base + lane index
                float b = img[sr1e[rr] + jl];
                tmp[rr * TSTRIDE + t] = a + srw[rr] * (b - a);
            }
        }
        __syncthreads();

        // Phase 2: horizontal (col) interp — ds_read2_b32 + 2 FMA + store.
        if (t < OUT_SZ) {
            float* __restrict__ orow = outS + (size_t)ch * PLANE;
            #pragma unroll
            for (int rr = 0; rr < RPB; ++rr) {
                const float* p = tmp + rr * TSTRIDE + c0;
                float hA = p[0];
                float hB = p[1];   // adjacent dword; pad col makes c1-clamp exact
                orow[(size_t)rr * OUT_SZ] = hA + wcl * (hB - hA);
            }
        }
        if (ch < 2) __syncthreads();     // protect tmp before next channel
    }
}

extern "C" void kernel_launch(void* const* d_in, const int* in_sizes, int n_in,
                              void* d_out, int out_size, void* d_ws, size_t ws_size,
                              hipStream_t stream) {
    const float* x   = (const float*)d_in[0];  // (32,3,299,299) fp32
    const int*   f   = (const int*)  d_in[1];  // (32,16,4) int32
    float*       out = (float*)d_out;          // (32,16,3,299,299) fp32

    dim3 grid(CHUNKS, 32 * 16);
    crop_resize_kernel<<<grid, 320, 0, stream>>>(x, f, out);
}